// Round 11
// baseline (202.733 us; speedup 1.0000x reference)
//
#include <hip/hip_runtime.h>

#define BATCH 16
#define TFRAMES 2000
#define BINS 513
#define NFFT 1024
#define STEP 256
#define OUT_LEN 512768            // (TFRAMES-1)*STEP + NFFT
#define M_TOTAL (BATCH*TFRAMES)   // 32000

typedef _Float16 f16x8 __attribute__((ext_vector_type(8)));
typedef float    f32x4 __attribute__((ext_vector_type(4)));

// ---------------------------------------------------------------------------
// Real 1024-pt inverse DFT per row via 512-pt complex synthesis DFT (radix-8^3).
// R8/R9/R10-verified math (passed, absmax 0.00098):
//   Z[q]   = (A[q] + i*w_q*B[q]) / 1024,  q=0..511
//            A = X[q] + conj(X[512-q]),  B = X[q] - conj(X[512-q]),
//            w_q = e^{+2pi i q/1024};  Z[0] = ((re0+re512) + i(re0-re512))/1024
//   y[m]   = sum_q Z[q] e^{+2pi i q m / 512};  x[2m]=Re y, x[2m+1]=Im y
//   frames[n] = x[n]*window[n]
// Radix-8^3 (q = q'+64q0, m = m0+8m', q'=a+8b, m'=c+8d), twiddles from the
// input idft tables: w_q = row1, W512^j = row2, w64^j = row16.
//
// ROUND 11 (schedule only, math identical): FOUR independent rows per wave
// ([4][8] register arrays, fully unrolled -> compile-time indices). The
// twice-verified ILP lever (R10: 2 rows/wave = +18%) applied again. LDS
// 73.7 KB/block -> 2 blocks/CU x 4 waves = same 32 rows in flight per CU,
// but 4 independent instruction streams per wave at every latency point;
// twiddle gathers amortized over 4 rows.
// ---------------------------------------------------------------------------

__device__ __forceinline__ void dft8(float* xr, float* xi) {
    // in-place 8-pt synthesis DFT: out[m] = sum_q in[q] e^{+2pi i q m/8}
    const float R = 0.70710678118654752f;
    float e0r = xr[0]+xr[4], e0i = xi[0]+xi[4];
    float e1r = xr[0]-xr[4], e1i = xi[0]-xi[4];
    float e2r = xr[2]+xr[6], e2i = xi[2]+xi[6];
    float e3r = xr[2]-xr[6], e3i = xi[2]-xi[6];
    float E0r = e0r+e2r, E0i = e0i+e2i;
    float E2r = e0r-e2r, E2i = e0i-e2i;
    float E1r = e1r-e3i, E1i = e1i+e3r;   // e1 + i e3
    float E3r = e1r+e3i, E3i = e1i-e3r;   // e1 - i e3
    float o0r = xr[1]+xr[5], o0i = xi[1]+xi[5];
    float o1r = xr[1]-xr[5], o1i = xi[1]-xi[5];
    float o2r = xr[3]+xr[7], o2i = xi[3]+xi[7];
    float o3r = xr[3]-xr[7], o3i = xi[3]-xi[7];
    float O0r = o0r+o2r, O0i = o0i+o2i;
    float O2r = o0r-o2r, O2i = o0i-o2i;
    float O1r = o1r-o3i, O1i = o1i+o3r;
    float O3r = o1r+o3i, O3i = o1i-o3r;
    // w8^m * O[m]:  w0=1, w1=R(1+i), w2=i, w3=R(-1+i)
    float T0r = O0r,            T0i = O0i;
    float T1r = R*(O1r-O1i),    T1i = R*(O1r+O1i);
    float T2r = -O2i,           T2i = O2r;
    float T3r = R*(-O3r-O3i),   T3i = R*(O3r-O3i);
    xr[0] = E0r+T0r; xi[0] = E0i+T0i;
    xr[4] = E0r-T0r; xi[4] = E0i-T0i;
    xr[1] = E1r+T1r; xi[1] = E1i+T1i;
    xr[5] = E1r-T1r; xi[5] = E1i-T1i;
    xr[2] = E2r+T2r; xi[2] = E2i+T2i;
    xr[6] = E2r-T2r; xi[6] = E2i-T2i;
    xr[3] = E3r+T3r; xi[3] = E3i+T3i;
    xr[7] = E3r-T3r; xi[7] = E3i-T3i;
}

__device__ __forceinline__ void async_copy4(const float* g, float* l) {
    __builtin_amdgcn_global_load_lds(
        (const __attribute__((address_space(1))) unsigned*)g,
        (__attribute__((address_space(3))) unsigned*)l, 4, 0, 0);
}

#define RPW 4                     // rows per wave
#define ROWS_PER_BLOCK 16         // 4 waves x RPW
#define LSTR 72                   // stage-layout row stride (verified R8-R10)

__global__ __launch_bounds__(256, 2) void fft_rows(const float* __restrict__ sre,
                                                   const float* __restrict__ sim,
                                                   const float* __restrict__ dcos,
                                                   const float* __restrict__ dsin,
                                                   const float* __restrict__ window,
                                                   _Float16* __restrict__ frames)
{
    // one 576-float buffer per row-slot, dual use:
    //   phase 0: [0..511]  = staged input X re/im
    //   stages : [m0*72+t] = working transform state
    __shared__ float LR[ROWS_PER_BLOCK][8 * LSTR];   // 36864 B
    __shared__ float LI[ROWS_PER_BLOCK][8 * LSTR];   // 36864 B

    const int tid = threadIdx.x;
    const int wv  = tid >> 6;                 // wave 0..3
    const int t   = tid & 63;                 // lane within wave
    const int r0  = wv * RPW;                 // this wave's row slots
    const int row0 = blockIdx.x * ROWS_PER_BLOCK + r0;

    const float* xr[RPW];
    const float* xi[RPW];
    #pragma unroll
    for (int rr = 0; rr < RPW; rr++) {
        xr[rr] = sre + (size_t)(row0 + rr) * BINS;
        xi[rr] = sim + (size_t)(row0 + rr) * BINS;
    }
    const float inv = 1.0f / 1024.0f;

    // ---- async-stage X[0..511] re/im for all rows (64 dword copies in flight;
    //      dest = wave-uniform base + lane*4, per global_load_lds rule) ----
    #pragma unroll
    for (int rr = 0; rr < RPW; rr++)
        #pragma unroll
        for (int k = 0; k < 8; k++) {
            async_copy4(xr[rr] + k*64 + t, &LR[r0 + rr][k*64 + t]);
            async_copy4(xi[rr] + k*64 + t, &LI[r0 + rr][k*64 + t]);
        }

    // independent scalar loads (issue alongside the async batch)
    float re0[RPW], re512[RPW];
    #pragma unroll
    for (int rr = 0; rr < RPW; rr++) { re0[rr] = xr[rr][0]; re512[rr] = xr[rr][512]; }
    float wc[8], ws[8];
    #pragma unroll
    for (int q0 = 0; q0 < 8; q0++) {
        const int q = t + 64 * q0;
        wc[q0] = dcos[1024 + q];              // w_q (row-invariant, L2-hot)
        ws[q0] = dsin[1024 + q];
    }
    __syncthreads();                          // staging landed (vmcnt drain)

    // ---- stage 1: build Z[t + 64*q0] from LDS, 8-pt DFT over q0, all rows ---
    float zr[RPW][8], zi[RPW][8];
    #pragma unroll
    for (int rr = 0; rr < RPW; rr++)
        #pragma unroll
        for (int q0 = 0; q0 < 8; q0++) {
            const int q = t + 64 * q0;
            float Zr, Zi;
            if (q == 0) {
                Zr = (re0[rr] + re512[rr]) * inv;
                Zi = (re0[rr] - re512[rr]) * inv;
            } else {
                const float xqr = LR[r0+rr][q],        xqi = LI[r0+rr][q];
                const float xmr = LR[r0+rr][512 - q],  xmi = LI[r0+rr][512 - q];
                const float Ar = xqr + xmr,  Ai = xqi - xmi;
                const float Br = xqr - xmr,  Bi = xqi + xmi;
                Zr = (Ar - ws[q0] * Br - wc[q0] * Bi) * inv;
                Zi = (Ai + wc[q0] * Br - ws[q0] * Bi) * inv;
            }
            zr[rr][q0] = Zr; zi[rr][q0] = Zi;
        }
    __syncthreads();                          // all input reads retired
    #pragma unroll
    for (int rr = 0; rr < RPW; rr++) dft8(zr[rr], zi[rr]);   // -> U[m0]

    // twiddle W512^{t*m0} (shared) and store to LDS as [m0][q'=t]
    #pragma unroll
    for (int m0 = 1; m0 < 8; m0++) {
        const int j = t * m0;                 // <= 441
        const float c = dcos[2048 + j], s = dsin[2048 + j];
        #pragma unroll
        for (int rr = 0; rr < RPW; rr++) {
            const float tr = zr[rr][m0] * c - zi[rr][m0] * s;
            zi[rr][m0] = zr[rr][m0] * s + zi[rr][m0] * c;
            zr[rr][m0] = tr;
        }
    }
    #pragma unroll
    for (int rr = 0; rr < RPW; rr++)
        #pragma unroll
        for (int m0 = 0; m0 < 8; m0++) {
            LR[r0+rr][m0*LSTR + t] = zr[rr][m0];
            LI[r0+rr][m0*LSTR + t] = zi[rr][m0];
        }
    __syncthreads();

    // ---- stage 2: per (m0, a): 8-pt DFT over b, twiddle w64^{ac}, all rows --
    const int m0 = t >> 3;
    const int a  = t & 7;
    float vr[RPW][8], vi[RPW][8];
    #pragma unroll
    for (int rr = 0; rr < RPW; rr++)
        #pragma unroll
        for (int b = 0; b < 8; b++) {
            vr[rr][b] = LR[r0+rr][m0*LSTR + a + 8*b];
            vi[rr][b] = LI[r0+rr][m0*LSTR + a + 8*b];
        }
    #pragma unroll
    for (int rr = 0; rr < RPW; rr++) dft8(vr[rr], vi[rr]);   // -> V[c]
    #pragma unroll
    for (int c = 1; c < 8; c++) {
        const int j = a * c;                  // <= 49
        const float cc = dcos[16*1024 + j], ss = dsin[16*1024 + j];
        #pragma unroll
        for (int rr = 0; rr < RPW; rr++) {
            const float tr = vr[rr][c] * cc - vi[rr][c] * ss;
            vi[rr][c] = vr[rr][c] * ss + vi[rr][c] * cc;
            vr[rr][c] = tr;
        }
    }
    __syncthreads();                          // all reads done before overwrite
    #pragma unroll
    for (int rr = 0; rr < RPW; rr++)
        #pragma unroll
        for (int c = 0; c < 8; c++) {
            LR[r0+rr][m0*LSTR + c*8 + a] = vr[rr][c];
            LI[r0+rr][m0*LSTR + c*8 + a] = vi[rr][c];
        }
    __syncthreads();

    // ---- stage 3: per (m0, c): 8-pt DFT over a -> y[m0 + 8c + 64d], all rows
    const int c3 = t & 7;
    float wr[RPW][8], wi[RPW][8];
    #pragma unroll
    for (int rr = 0; rr < RPW; rr++)
        #pragma unroll
        for (int a2 = 0; a2 < 8; a2++) {
            wr[rr][a2] = LR[r0+rr][m0*LSTR + c3*8 + a2];
            wi[rr][a2] = LI[r0+rr][m0*LSTR + c3*8 + a2];
        }
    #pragma unroll
    for (int rr = 0; rr < RPW; rr++) dft8(wr[rr], wi[rr]);   // -> y[d]

    // ---- windowed f16 store: x[2m]=Re, x[2m+1]=Im, m = m0+8c+64d, all rows --
    #pragma unroll
    for (int rr = 0; rr < RPW; rr++) {
        const size_t fbase = (size_t)(row0 + rr) * NFFT;
        #pragma unroll
        for (int d = 0; d < 8; d++) {
            const int n = 2 * (m0 + 8*c3 + 64*d);
            const float2 wv = *(const float2*)&window[n];
            union { _Float16 h[2]; unsigned u; } pk;
            pk.h[0] = (_Float16)(wr[rr][d] * wv.x);
            pk.h[1] = (_Float16)(wi[rr][d] * wv.y);
            *(unsigned*)&frames[fbase + n] = pk.u;
        }
    }
}

// ---------------- deterministic overlap-add gather (verified R0-R10) --------
#define OLA_G 64096   // OUT_LEN/8
__global__ __launch_bounds__(256) void ola_gather(const _Float16* __restrict__ frames,
                                                  float* __restrict__ out)
{
    const int idx = blockIdx.x * 256 + threadIdx.x;   // b*OLA_G + r, exact grid
    const int b = idx / OLA_G;
    const int r = idx - b * OLA_G;
    const int s0 = r << 3;
    int tlo = (s0 - 768) >> 8;  if (tlo < 0) tlo = 0;
    int thi = s0 >> 8;          if (thi > TFRAMES-1) thi = TFRAMES-1;
    float sum[8] = {};
    for (int t = tlo; t <= thi; ++t) {
        const f16x8 f = *(const f16x8*)&frames[((size_t)b * TFRAMES + t) * NFFT + (s0 - (t << 8))];
        #pragma unroll
        for (int i = 0; i < 8; i++) sum[i] += (float)f[i];
    }
    f32x4* o = (f32x4*)(out + (size_t)b * OUT_LEN + s0);
    o[0] = (f32x4){sum[0], sum[1], sum[2], sum[3]};
    o[1] = (f32x4){sum[4], sum[5], sum[6], sum[7]};
}

// ---------------- round-1 fp32 fallback (known-correct, needs no ws) --------
#define MT 64
#define NT 64
#define KT 16
#define PAD 4
__global__ __launch_bounds__(256) void istft_gemm_ola_f32(
    const float* __restrict__ sre, const float* __restrict__ sim,
    const float* __restrict__ dcos, const float* __restrict__ dsin,
    const float* __restrict__ window, float* __restrict__ out)
{
    __shared__ float As_re[KT][MT + PAD];
    __shared__ float As_im[KT][MT + PAD];
    __shared__ float Bs_c[KT][NT + PAD];
    __shared__ float Bs_s[KT][NT + PAD];
    const int ntile = blockIdx.x & 15;
    const int mtile = blockIdx.x >> 4;
    const int m0 = mtile * MT, n0 = ntile * NT;
    const int tid = threadIdx.x;
    const int tx = tid & 15, ty = tid >> 4;
    const int lcol = tid & 15, lrow = tid >> 4;
    float acc[4][4] = {};
    for (int k0 = 0; k0 < BINS; k0 += KT) {
        const int k = k0 + lcol;
        const bool kvalid = (k < BINS);
        const float w = kvalid ? ((k == 0 || k == 512) ? (1.0f/1024.0f) : (2.0f/1024.0f)) : 0.0f;
        #pragma unroll
        for (int i = 0; i < 4; i++) {
            const int m = m0 + lrow + i*16;
            const size_t base = (size_t)m * BINS + k;
            As_re[lcol][lrow + i*16] = kvalid ?  w * sre[base] : 0.0f;
            As_im[lcol][lrow + i*16] = kvalid ? -w * sim[base] : 0.0f;
        }
        #pragma unroll
        for (int i = 0; i < 4; i++) {
            const int n = n0 + lrow + i*16;
            const size_t base = (size_t)n * NFFT + k;
            Bs_c[lcol][lrow + i*16] = kvalid ? dcos[base] : 0.0f;
            Bs_s[lcol][lrow + i*16] = kvalid ? dsin[base] : 0.0f;
        }
        __syncthreads();
        #pragma unroll
        for (int kk = 0; kk < KT; kk++) {
            const float4 ar = *(const float4*)&As_re[kk][ty*4];
            const float4 ai = *(const float4*)&As_im[kk][ty*4];
            const float4 bc = *(const float4*)&Bs_c[kk][tx*4];
            const float4 bs = *(const float4*)&Bs_s[kk][tx*4];
            const float a_r[4] = {ar.x, ar.y, ar.z, ar.w};
            const float a_i[4] = {ai.x, ai.y, ai.z, ai.w};
            const float b_c[4] = {bc.x, bc.y, bc.z, bc.w};
            const float b_s[4] = {bs.x, bs.y, bs.z, bs.w};
            #pragma unroll
            for (int i = 0; i < 4; i++)
                #pragma unroll
                for (int j = 0; j < 4; j++)
                    acc[i][j] += a_r[i]*b_c[j] + a_i[i]*b_s[j];
        }
        __syncthreads();
    }
    #pragma unroll
    for (int i = 0; i < 4; i++) {
        const int m = m0 + ty*4 + i;
        const int b = m / TFRAMES;
        const int t = m - b * TFRAMES;
        const size_t obase = (size_t)b * OUT_LEN + (size_t)t * STEP;
        #pragma unroll
        for (int j = 0; j < 4; j++) {
            const int n = n0 + tx*4 + j;
            atomicAdd(&out[obase + n], acc[i][j] * window[n]);
        }
    }
}

// ---------------- launch ----------------
extern "C" void kernel_launch(void* const* d_in, const int* in_sizes, int n_in,
                              void* d_out, int out_size, void* d_ws, size_t ws_size,
                              hipStream_t stream) {
    const float* sre    = (const float*)d_in[0];
    const float* sim    = (const float*)d_in[1];
    const float* dcos   = (const float*)d_in[2];
    const float* dsin   = (const float*)d_in[3];
    const float* window = (const float*)d_in[4];
    float* out = (float*)d_out;

    const size_t WS_FR = (size_t)M_TOTAL * NFFT * sizeof(_Float16);   // 65,536,000

    if (ws_size >= WS_FR) {
        _Float16* fr = (_Float16*)d_ws;
        fft_rows<<<M_TOTAL / ROWS_PER_BLOCK, 256, 0, stream>>>(
            sre, sim, dcos, dsin, window, fr);
        ola_gather<<<(BATCH * OUT_LEN) / 2048, 256, 0, stream>>>(fr, out);
    } else {
        hipMemsetAsync(out, 0, (size_t)out_size * sizeof(float), stream);
        const int grid = (M_TOTAL / MT) * 16;
        istft_gemm_ola_f32<<<grid, 256, 0, stream>>>(sre, sim, dcos, dsin, window, out);
    }
}

// Round 12
// 186.160 us; speedup vs baseline: 1.0890x; 1.0890x over previous
//
#include <hip/hip_runtime.h>

#define BATCH 16
#define TFRAMES 2000
#define BINS 513
#define NFFT 1024
#define STEP 256
#define OUT_LEN 512768            // (TFRAMES-1)*STEP + NFFT
#define M_TOTAL (BATCH*TFRAMES)   // 32000

typedef _Float16 f16x8 __attribute__((ext_vector_type(8)));
typedef float    f32x4 __attribute__((ext_vector_type(4)));

// ---------------------------------------------------------------------------
// Real 1024-pt inverse DFT per row via 512-pt complex synthesis DFT (radix-8^3).
// R8-R11-verified math (passed, absmax 0.00098):
//   Z[q]   = (A[q] + i*w_q*B[q]) / 1024,  q=0..511
//            A = X[q] + conj(X[512-q]),  B = X[q] - conj(X[512-q]),
//            w_q = e^{+2pi i q/1024};  Z[0] = ((re0+re512) + i(re0-re512))/1024
//   y[m]   = sum_q Z[q] e^{+2pi i q m / 512};  x[2m]=Re y, x[2m+1]=Im y
//   frames[n] = x[n]*window[n]
// Radix-8^3: q = q'+64q0, m = m0+8m', q'=a+8b, m'=c+8d.
//
// ROUND 12 (schedule only, math identical to R10's 2-rows/wave config):
//  1. NO __syncthreads: each wave owns its LDS row slots exclusively; the
//     only sync needed is the wave-local s_waitcnt vmcnt(0) after its own
//     global_load_lds batch. Same-wave LDS read-then-overwrite is safe by
//     in-order per-wave DS processing + program order (compiler fences keep
//     source order). Waves free-run and cover each other's stalls.
//  2. Twiddles computed with v_cos_f32/v_sin_f32 (input = revolutions,
//     all args < 1 so no range reduction): replaces the multi-cache-line
//     dcos/dsin gathers with cheap transcendentals on the idle VALU pipe.
// ---------------------------------------------------------------------------

__device__ __forceinline__ float hw_cos(float rev) {   // cos(2*pi*rev)
    float r; asm("v_cos_f32 %0, %1" : "=v"(r) : "v"(rev)); return r;
}
__device__ __forceinline__ float hw_sin(float rev) {   // sin(2*pi*rev)
    float r; asm("v_sin_f32 %0, %1" : "=v"(r) : "v"(rev)); return r;
}

__device__ __forceinline__ void dft8(float* xr, float* xi) {
    // in-place 8-pt synthesis DFT: out[m] = sum_q in[q] e^{+2pi i q m/8}
    const float R = 0.70710678118654752f;
    float e0r = xr[0]+xr[4], e0i = xi[0]+xi[4];
    float e1r = xr[0]-xr[4], e1i = xi[0]-xi[4];
    float e2r = xr[2]+xr[6], e2i = xi[2]+xi[6];
    float e3r = xr[2]-xr[6], e3i = xi[2]-xi[6];
    float E0r = e0r+e2r, E0i = e0i+e2i;
    float E2r = e0r-e2r, E2i = e0i-e2i;
    float E1r = e1r-e3i, E1i = e1i+e3r;   // e1 + i e3
    float E3r = e1r+e3i, E3i = e1i-e3r;   // e1 - i e3
    float o0r = xr[1]+xr[5], o0i = xi[1]+xi[5];
    float o1r = xr[1]-xr[5], o1i = xi[1]-xi[5];
    float o2r = xr[3]+xr[7], o2i = xi[3]+xi[7];
    float o3r = xr[3]-xr[7], o3i = xi[3]-xi[7];
    float O0r = o0r+o2r, O0i = o0i+o2i;
    float O2r = o0r-o2r, O2i = o0i-o2i;
    float O1r = o1r-o3i, O1i = o1i+o3r;
    float O3r = o1r+o3i, O3i = o1i-o3r;
    // w8^m * O[m]:  w0=1, w1=R(1+i), w2=i, w3=R(-1+i)
    float T0r = O0r,            T0i = O0i;
    float T1r = R*(O1r-O1i),    T1i = R*(O1r+O1i);
    float T2r = -O2i,           T2i = O2r;
    float T3r = R*(-O3r-O3i),   T3i = R*(O3r-O3i);
    xr[0] = E0r+T0r; xi[0] = E0i+T0i;
    xr[4] = E0r-T0r; xi[4] = E0i-T0i;
    xr[1] = E1r+T1r; xi[1] = E1i+T1i;
    xr[5] = E1r-T1r; xi[5] = E1i-T1i;
    xr[2] = E2r+T2r; xi[2] = E2i+T2i;
    xr[6] = E2r-T2r; xi[6] = E2i-T2i;
    xr[3] = E3r+T3r; xi[3] = E3i+T3i;
    xr[7] = E3r-T3r; xi[7] = E3i-T3i;
}

__device__ __forceinline__ void async_copy4(const float* g, float* l) {
    __builtin_amdgcn_global_load_lds(
        (const __attribute__((address_space(1))) unsigned*)g,
        (__attribute__((address_space(3))) unsigned*)l, 4, 0, 0);
}

#define RPW 2                     // rows per wave (R10-verified sweet spot)
#define ROWS_PER_BLOCK 8          // 4 waves x RPW
#define LSTR 72                   // stage-layout row stride (verified R8-R11)

__global__ __launch_bounds__(256, 4) void fft_rows(const float* __restrict__ sre,
                                                   const float* __restrict__ sim,
                                                   const float* __restrict__ window,
                                                   _Float16* __restrict__ frames)
{
    // one 576-float buffer per row-slot, dual use:
    //   phase 0: [0..511]  = staged input X re/im
    //   stages : [m0*72+t] = working transform state
    // Row slots are WAVE-PRIVATE: wave wv owns slots [2wv, 2wv+1] only.
    __shared__ float LR[ROWS_PER_BLOCK][8 * LSTR];   // 18432 B
    __shared__ float LI[ROWS_PER_BLOCK][8 * LSTR];   // 18432 B

    const int tid = threadIdx.x;
    const int wv  = tid >> 6;                 // wave 0..3
    const int t   = tid & 63;                 // lane within wave
    const int r0  = wv * RPW;                 // this wave's row slots
    const int row0 = blockIdx.x * ROWS_PER_BLOCK + r0;

    const float* xr[RPW];
    const float* xi[RPW];
    #pragma unroll
    for (int rr = 0; rr < RPW; rr++) {
        xr[rr] = sre + (size_t)(row0 + rr) * BINS;
        xi[rr] = sim + (size_t)(row0 + rr) * BINS;
    }
    const float inv = 1.0f / 1024.0f;

    // ---- async-stage X[0..511] re/im for both rows (32 dword copies in
    //      flight; dest = wave-uniform base + lane*4, global_load_lds rule) --
    #pragma unroll
    for (int rr = 0; rr < RPW; rr++)
        #pragma unroll
        for (int k = 0; k < 8; k++) {
            async_copy4(xr[rr] + k*64 + t, &LR[r0 + rr][k*64 + t]);
            async_copy4(xi[rr] + k*64 + t, &LI[r0 + rr][k*64 + t]);
        }

    // independent scalar loads + computed w_q twiddles (VALU, no gathers)
    float re0[RPW], re512[RPW];
    #pragma unroll
    for (int rr = 0; rr < RPW; rr++) { re0[rr] = xr[rr][0]; re512[rr] = xr[rr][512]; }
    float wc[8], ws[8];
    #pragma unroll
    for (int q0 = 0; q0 < 8; q0++) {
        const float qrev = (float)(t + 64 * q0) * (1.0f/1024.0f);  // < 1
        wc[q0] = hw_cos(qrev);                // w_q = e^{+2pi i q/1024}
        ws[q0] = hw_sin(qrev);
    }
    // wave-local drain of this wave's own global_load_lds batch
    asm volatile("s_waitcnt vmcnt(0)" ::: "memory");

    // ---- stage 1: build Z[t + 64*q0] from LDS, 8-pt DFT over q0, both rows -
    float zr[RPW][8], zi[RPW][8];
    #pragma unroll
    for (int rr = 0; rr < RPW; rr++)
        #pragma unroll
        for (int q0 = 0; q0 < 8; q0++) {
            const int q = t + 64 * q0;
            float Zr, Zi;
            if (q == 0) {
                Zr = (re0[rr] + re512[rr]) * inv;
                Zi = (re0[rr] - re512[rr]) * inv;
            } else {
                const float xqr = LR[r0+rr][q],        xqi = LI[r0+rr][q];
                const float xmr = LR[r0+rr][512 - q],  xmi = LI[r0+rr][512 - q];
                const float Ar = xqr + xmr,  Ai = xqi - xmi;
                const float Br = xqr - xmr,  Bi = xqi + xmi;
                Zr = (Ar - ws[q0] * Br - wc[q0] * Bi) * inv;
                Zi = (Ai + wc[q0] * Br - ws[q0] * Bi) * inv;
            }
            zr[rr][q0] = Zr; zi[rr][q0] = Zi;
        }
    asm volatile("" ::: "memory");            // compiler fence: reads before overwrite
    #pragma unroll
    for (int rr = 0; rr < RPW; rr++) dft8(zr[rr], zi[rr]);   // -> U[m0]

    // twiddle W512^{t*m0} (computed) and store to LDS as [m0][q'=t]
    #pragma unroll
    for (int m0 = 1; m0 < 8; m0++) {
        const float jrev = (float)(t * m0) * (1.0f/512.0f);   // <= 441/512 < 1
        const float c = hw_cos(jrev), s = hw_sin(jrev);
        #pragma unroll
        for (int rr = 0; rr < RPW; rr++) {
            const float tr = zr[rr][m0] * c - zi[rr][m0] * s;
            zi[rr][m0] = zr[rr][m0] * s + zi[rr][m0] * c;
            zr[rr][m0] = tr;
        }
    }
    #pragma unroll
    for (int rr = 0; rr < RPW; rr++)
        #pragma unroll
        for (int m0 = 0; m0 < 8; m0++) {
            LR[r0+rr][m0*LSTR + t] = zr[rr][m0];
            LI[r0+rr][m0*LSTR + t] = zi[rr][m0];
        }
    asm volatile("" ::: "memory");            // writes before stage-2 reads (same wave)

    // ---- stage 2: per (m0, a): 8-pt DFT over b, twiddle w64^{ac}, both rows
    const int m0 = t >> 3;
    const int a  = t & 7;
    float vr[RPW][8], vi[RPW][8];
    #pragma unroll
    for (int rr = 0; rr < RPW; rr++)
        #pragma unroll
        for (int b = 0; b < 8; b++) {
            vr[rr][b] = LR[r0+rr][m0*LSTR + a + 8*b];
            vi[rr][b] = LI[r0+rr][m0*LSTR + a + 8*b];
        }
    #pragma unroll
    for (int rr = 0; rr < RPW; rr++) dft8(vr[rr], vi[rr]);   // -> V[c]
    #pragma unroll
    for (int c = 1; c < 8; c++) {
        const float jrev = (float)(a * c) * (1.0f/64.0f);     // <= 49/64 < 1
        const float cc = hw_cos(jrev), ss = hw_sin(jrev);
        #pragma unroll
        for (int rr = 0; rr < RPW; rr++) {
            const float tr = vr[rr][c] * cc - vi[rr][c] * ss;
            vi[rr][c] = vr[rr][c] * ss + vi[rr][c] * cc;
            vr[rr][c] = tr;
        }
    }
    asm volatile("" ::: "memory");            // reads before overwrite (same wave)
    #pragma unroll
    for (int rr = 0; rr < RPW; rr++)
        #pragma unroll
        for (int c = 0; c < 8; c++) {
            LR[r0+rr][m0*LSTR + c*8 + a] = vr[rr][c];
            LI[r0+rr][m0*LSTR + c*8 + a] = vi[rr][c];
        }
    asm volatile("" ::: "memory");            // writes before stage-3 reads (same wave)

    // ---- stage 3: per (m0, c): 8-pt DFT over a -> y[m0 + 8c + 64d], both rows
    const int c3 = t & 7;
    float wr[RPW][8], wi[RPW][8];
    #pragma unroll
    for (int rr = 0; rr < RPW; rr++)
        #pragma unroll
        for (int a2 = 0; a2 < 8; a2++) {
            wr[rr][a2] = LR[r0+rr][m0*LSTR + c3*8 + a2];
            wi[rr][a2] = LI[r0+rr][m0*LSTR + c3*8 + a2];
        }
    #pragma unroll
    for (int rr = 0; rr < RPW; rr++) dft8(wr[rr], wi[rr]);   // -> y[d]

    // ---- windowed f16 store: x[2m]=Re, x[2m+1]=Im, m = m0+8c+64d, both rows
    #pragma unroll
    for (int rr = 0; rr < RPW; rr++) {
        const size_t fbase = (size_t)(row0 + rr) * NFFT;
        #pragma unroll
        for (int d = 0; d < 8; d++) {
            const int n = 2 * (m0 + 8*c3 + 64*d);
            const float2 wv = *(const float2*)&window[n];
            union { _Float16 h[2]; unsigned u; } pk;
            pk.h[0] = (_Float16)(wr[rr][d] * wv.x);
            pk.h[1] = (_Float16)(wi[rr][d] * wv.y);
            *(unsigned*)&frames[fbase + n] = pk.u;
        }
    }
}

// ---------------- deterministic overlap-add gather (verified R0-R11) --------
#define OLA_G 64096   // OUT_LEN/8
__global__ __launch_bounds__(256) void ola_gather(const _Float16* __restrict__ frames,
                                                  float* __restrict__ out)
{
    const int idx = blockIdx.x * 256 + threadIdx.x;   // b*OLA_G + r, exact grid
    const int b = idx / OLA_G;
    const int r = idx - b * OLA_G;
    const int s0 = r << 3;
    int tlo = (s0 - 768) >> 8;  if (tlo < 0) tlo = 0;
    int thi = s0 >> 8;          if (thi > TFRAMES-1) thi = TFRAMES-1;
    float sum[8] = {};
    for (int t = tlo; t <= thi; ++t) {
        const f16x8 f = *(const f16x8*)&frames[((size_t)b * TFRAMES + t) * NFFT + (s0 - (t << 8))];
        #pragma unroll
        for (int i = 0; i < 8; i++) sum[i] += (float)f[i];
    }
    f32x4* o = (f32x4*)(out + (size_t)b * OUT_LEN + s0);
    o[0] = (f32x4){sum[0], sum[1], sum[2], sum[3]};
    o[1] = (f32x4){sum[4], sum[5], sum[6], sum[7]};
}

// ---------------- round-1 fp32 fallback (known-correct, needs no ws) --------
#define MT 64
#define NT 64
#define KT 16
#define PAD 4
__global__ __launch_bounds__(256) void istft_gemm_ola_f32(
    const float* __restrict__ sre, const float* __restrict__ sim,
    const float* __restrict__ dcos, const float* __restrict__ dsin,
    const float* __restrict__ window, float* __restrict__ out)
{
    __shared__ float As_re[KT][MT + PAD];
    __shared__ float As_im[KT][MT + PAD];
    __shared__ float Bs_c[KT][NT + PAD];
    __shared__ float Bs_s[KT][NT + PAD];
    const int ntile = blockIdx.x & 15;
    const int mtile = blockIdx.x >> 4;
    const int m0 = mtile * MT, n0 = ntile * NT;
    const int tid = threadIdx.x;
    const int tx = tid & 15, ty = tid >> 4;
    const int lcol = tid & 15, lrow = tid >> 4;
    float acc[4][4] = {};
    for (int k0 = 0; k0 < BINS; k0 += KT) {
        const int k = k0 + lcol;
        const bool kvalid = (k < BINS);
        const float w = kvalid ? ((k == 0 || k == 512) ? (1.0f/1024.0f) : (2.0f/1024.0f)) : 0.0f;
        #pragma unroll
        for (int i = 0; i < 4; i++) {
            const int m = m0 + lrow + i*16;
            const size_t base = (size_t)m * BINS + k;
            As_re[lcol][lrow + i*16] = kvalid ?  w * sre[base] : 0.0f;
            As_im[lcol][lrow + i*16] = kvalid ? -w * sim[base] : 0.0f;
        }
        #pragma unroll
        for (int i = 0; i < 4; i++) {
            const int n = n0 + lrow + i*16;
            const size_t base = (size_t)n * NFFT + k;
            Bs_c[lcol][lrow + i*16] = kvalid ? dcos[base] : 0.0f;
            Bs_s[lcol][lrow + i*16] = kvalid ? dsin[base] : 0.0f;
        }
        __syncthreads();
        #pragma unroll
        for (int kk = 0; kk < KT; kk++) {
            const float4 ar = *(const float4*)&As_re[kk][ty*4];
            const float4 ai = *(const float4*)&As_im[kk][ty*4];
            const float4 bc = *(const float4*)&Bs_c[kk][tx*4];
            const float4 bs = *(const float4*)&Bs_s[kk][tx*4];
            const float a_r[4] = {ar.x, ar.y, ar.z, ar.w};
            const float a_i[4] = {ai.x, ai.y, ai.z, ai.w};
            const float b_c[4] = {bc.x, bc.y, bc.z, bc.w};
            const float b_s[4] = {bs.x, bs.y, bs.z, bs.w};
            #pragma unroll
            for (int i = 0; i < 4; i++)
                #pragma unroll
                for (int j = 0; j < 4; j++)
                    acc[i][j] += a_r[i]*b_c[j] + a_i[i]*b_s[j];
        }
        __syncthreads();
    }
    #pragma unroll
    for (int i = 0; i < 4; i++) {
        const int m = m0 + ty*4 + i;
        const int b = m / TFRAMES;
        const int t = m - b * TFRAMES;
        const size_t obase = (size_t)b * OUT_LEN + (size_t)t * STEP;
        #pragma unroll
        for (int j = 0; j < 4; j++) {
            const int n = n0 + tx*4 + j;
            atomicAdd(&out[obase + n], acc[i][j] * window[n]);
        }
    }
}

// ---------------- launch ----------------
extern "C" void kernel_launch(void* const* d_in, const int* in_sizes, int n_in,
                              void* d_out, int out_size, void* d_ws, size_t ws_size,
                              hipStream_t stream) {
    const float* sre    = (const float*)d_in[0];
    const float* sim    = (const float*)d_in[1];
    const float* dcos   = (const float*)d_in[2];
    const float* dsin   = (const float*)d_in[3];
    const float* window = (const float*)d_in[4];
    float* out = (float*)d_out;

    const size_t WS_FR = (size_t)M_TOTAL * NFFT * sizeof(_Float16);   // 65,536,000

    if (ws_size >= WS_FR) {
        _Float16* fr = (_Float16*)d_ws;
        fft_rows<<<M_TOTAL / ROWS_PER_BLOCK, 256, 0, stream>>>(
            sre, sim, window, fr);
        ola_gather<<<(BATCH * OUT_LEN) / 2048, 256, 0, stream>>>(fr, out);
    } else {
        hipMemsetAsync(out, 0, (size_t)out_size * sizeof(float), stream);
        const int grid = (M_TOTAL / MT) * 16;
        istft_gemm_ola_f32<<<grid, 256, 0, stream>>>(sre, sim, dcos, dsin, window, out);
    }
}